// Round 3
// baseline (616.385 us; speedup 1.0000x reference)
//
#include <hip/hip_runtime.h>

#define NN 100000
#define NE 1600000
#define ENT (NE + NN)   // edges + self loops

// ---------------- CSR build ----------------

__global__ void probe_kernel(const unsigned* __restrict__ edges, int* __restrict__ flag) {
    if (threadIdx.x == 0 && blockIdx.x == 0) {
        int is64 = 1;
        for (int i = 1; i < 64; i += 2)
            if (edges[i] != 0u) { is64 = 0; break; }
        *flag = is64;
    }
}

// count in-degree from the dst half of the raw edge list (int64 or int32)
__global__ void count_kernel(const void* __restrict__ edges, const int* __restrict__ flag,
                             int* __restrict__ cnt) {
    int i = blockIdx.x * blockDim.x + threadIdx.x;
    if (i >= NE) return;
    int d;
    if (*flag) d = (int)((const long long*)edges)[NE + i];
    else       d = ((const int*)edges)[NE + i];
    atomicAdd(&cnt[d], 1);
}

__global__ void dinv_kernel(const int* __restrict__ cnt, float* __restrict__ dinv) {
    int i = blockIdx.x * blockDim.x + threadIdx.x;
    if (i < NN) dinv[i] = rsqrtf((float)(cnt[i] + 1));  // +1 self loop, always > 0
}

__global__ __launch_bounds__(1024) void scan_local(const int* __restrict__ cnt,
                                                   int* __restrict__ rowoff,
                                                   int* __restrict__ part) {
    __shared__ int s[1024];
    int t = threadIdx.x;
    int i = blockIdx.x * 1024 + t;
    int v = (i < NN) ? cnt[i] + 1 : 0;
    s[t] = v;
    __syncthreads();
    for (int off = 1; off < 1024; off <<= 1) {
        int a = (t >= off) ? s[t - off] : 0;
        __syncthreads();
        s[t] += a;
        __syncthreads();
    }
    if (i < NN) rowoff[i] = s[t] - v;     // exclusive (local)
    if (t == 1023) part[blockIdx.x] = s[t];
}

__global__ void scan_part(int* __restrict__ part, int nb) {
    __shared__ int s[128];
    int t = threadIdx.x;
    int v = (t < nb) ? part[t] : 0;
    s[t] = v;
    __syncthreads();
    for (int off = 1; off < 128; off <<= 1) {
        int a = (t >= off) ? s[t - off] : 0;
        __syncthreads();
        s[t] += a;
        __syncthreads();
    }
    if (t < nb) part[t] = s[t] - v;       // exclusive
}

// finalize rowoff AND initialize the fill cursor to the same offsets
__global__ void scan_add(int* __restrict__ rowoff, int* __restrict__ cursor,
                         const int* __restrict__ part) {
    int i = blockIdx.x * blockDim.x + threadIdx.x;
    if (i < NN) {
        int v = rowoff[i] + part[i >> 10];
        rowoff[i] = v;
        cursor[i] = v;
    }
    if (i == 0) rowoff[NN] = ENT;
}

// one packed 8B scatter per edge: (src, norm-bits); reads raw edges directly
__global__ void fill_kernel(const void* __restrict__ edges, const int* __restrict__ flag,
                            const float* __restrict__ dinv,
                            int* __restrict__ cursor, int2* __restrict__ edge) {
    int i = blockIdx.x * blockDim.x + threadIdx.x;
    if (i >= ENT) return;
    int s, j;
    if (i < NE) {
        if (*flag) {
            s = (int)((const long long*)edges)[i];
            j = (int)((const long long*)edges)[NE + i];
        } else {
            s = ((const int*)edges)[i];
            j = ((const int*)edges)[NE + i];
        }
    } else {
        s = i - NE; j = s;
    }
    int p = atomicAdd(&cursor[j], 1);
    float v = dinv[s] * dinv[j];
    edge[p] = make_int2(s, __float_as_int(v));
}

// ---------------- collapsed weights: WcT[64][128], Wc = W1^T W1^T W2^T ----------------
// T[k][j]  = sum_q W1[q][k] * W2[j][q]        (T = W1^T W2^T, [128][64])
// WcT[j][i] = sum_k W1[k][i] * T[k][j]         (Wc = W1^T T, stored transposed [64][128])
__global__ __launch_bounds__(256) void smallw_kernel(const float* __restrict__ W1,
                                                     const float* __restrict__ W2,
                                                     float* __restrict__ T,
                                                     float* __restrict__ WcT) {
    int t = threadIdx.x;
    for (int idx = t; idx < 128 * 64; idx += 256) {
        int k = idx >> 6, j = idx & 63;
        float s = 0.f;
        for (int q = 0; q < 128; ++q)
            s += W1[q * 128 + k] * W2[j * 128 + q];
        T[k * 64 + j] = s;
    }
    __syncthreads();
    for (int idx = t; idx < 128 * 64; idx += 256) {
        int i = idx >> 6, j = idx & 63;
        float s = 0.f;
        for (int k = 0; k < 128; ++k)
            s += W1[k * 128 + i] * T[k * 64 + j];
        WcT[j * 128 + i] = s;
    }
}

// ---------------- propagate (F=64): one wave per node, lane = feature ----------------

__global__ __launch_bounds__(256) void spmm64_kernel(const int* __restrict__ rowoff,
                                                     const int2* __restrict__ edge,
                                                     const float* __restrict__ H,
                                                     float* __restrict__ O) {
    int w = (int)((blockIdx.x * (unsigned)blockDim.x + threadIdx.x) >> 6);
    if (w >= NN) return;
    int lane = threadIdx.x & 63;
    int s = rowoff[w], e = rowoff[w + 1];
    float acc = 0.f;
    const float* base = H + lane;

    int p = s;
    for (; p + 8 <= e; p += 8) {
        int2 E[8];
        #pragma unroll
        for (int q = 0; q < 8; ++q) E[q] = edge[p + q];
        #pragma unroll
        for (int q = 0; q < 8; ++q)
            acc += __int_as_float(E[q].y) * base[(size_t)E[q].x * 64];
    }
    if (p + 4 <= e) {
        int2 E[4];
        #pragma unroll
        for (int q = 0; q < 4; ++q) E[q] = edge[p + q];
        #pragma unroll
        for (int q = 0; q < 4; ++q)
            acc += __int_as_float(E[q].y) * base[(size_t)E[q].x * 64];
        p += 4;
    }
    for (; p < e; ++p) {
        int2 E = edge[p];
        acc += __int_as_float(E.y) * base[(size_t)E.x * 64];
    }
    O[(size_t)w * 64 + lane] = acc;
}

// ---------------- fp32 GEMM: Y[M,N] = X[M,128] @ W[N,128]^T ----------------

template<int N>   // N = 128 or 64
__global__ __launch_bounds__(256) void gemm_xwt(const float* __restrict__ X,
                                                const float* __restrict__ W,
                                                float* __restrict__ Y, int M) {
    constexpr int K = 128, BM = 64, BK = 32;
    constexpr int TM = 4, TN = N / 16;
    __shared__ float Xs[BK][BM + 4];
    __shared__ float Ws[BK][N + 4];
    int t  = threadIdx.x;
    int m0 = blockIdx.x * BM;
    int r0 = (t >> 4) * TM;
    int c0 = (t & 15) * TN;
    float acc[TM][TN] = {};
    for (int k0 = 0; k0 < K; k0 += BK) {
        #pragma unroll
        for (int i = 0; i < 2; ++i) {            // X tile: 512 float4
            int f  = t + i * 256;
            int m  = f >> 3;
            int kq = (f & 7) << 2;
            int gm = m0 + m; if (gm >= M) gm = M - 1;
            float4 v = *(const float4*)&X[(size_t)gm * K + k0 + kq];
            Xs[kq + 0][m] = v.x; Xs[kq + 1][m] = v.y;
            Xs[kq + 2][m] = v.z; Xs[kq + 3][m] = v.w;
        }
        #pragma unroll
        for (int i = 0; i < N / 32; ++i) {       // W tile: N*8 float4
            int f  = t + i * 256;
            int n  = f >> 3;
            int kq = (f & 7) << 2;
            float4 v = *(const float4*)&W[(size_t)n * K + k0 + kq];
            Ws[kq + 0][n] = v.x; Ws[kq + 1][n] = v.y;
            Ws[kq + 2][n] = v.z; Ws[kq + 3][n] = v.w;
        }
        __syncthreads();
        #pragma unroll
        for (int k = 0; k < BK; ++k) {
            float4 xv = *(const float4*)&Xs[k][r0];
            float xf[TM] = {xv.x, xv.y, xv.z, xv.w};
            float wf[TN];
            #pragma unroll
            for (int j = 0; j < TN; j += 4) {
                float4 wv = *(const float4*)&Ws[k][c0 + j];
                wf[j] = wv.x; wf[j + 1] = wv.y; wf[j + 2] = wv.z; wf[j + 3] = wv.w;
            }
            #pragma unroll
            for (int i = 0; i < TM; ++i)
                #pragma unroll
                for (int j = 0; j < TN; ++j)
                    acc[i][j] += xf[i] * wf[j];
        }
        __syncthreads();
    }
    #pragma unroll
    for (int i = 0; i < TM; ++i) {
        int gm = m0 + r0 + i;
        if (gm < M) {
            #pragma unroll
            for (int j = 0; j < TN; j += 4) {
                float4 v = {acc[i][j], acc[i][j + 1], acc[i][j + 2], acc[i][j + 3]};
                *(float4*)&Y[(size_t)gm * N + c0 + j] = v;
            }
        }
    }
}

// ---------------- launch ----------------

extern "C" void kernel_launch(void* const* d_in, const int* in_sizes, int n_in,
                              void* d_out, int out_size, void* d_ws, size_t ws_size,
                              hipStream_t stream) {
    const float* x     = (const float*)d_in[0];
    const void*  edges = d_in[1];
    const float* W1    = (const float*)d_in[2];
    const float* W2    = (const float*)d_in[3];
    float* out = (float*)d_out;

    char* ws = (char*)d_ws;
    size_t off = 0;
    auto take = [&](size_t bytes) -> char* {
        char* p = ws + off;
        off = (off + bytes + 255) & ~(size_t)255;
        return p;
    };
    int*   flag   = (int*)take(4);
    int*   cnt    = (int*)take((size_t)NN * 4);        // degree counts, then fill cursor
    float* dinv   = (float*)take((size_t)NN * 4);
    int*   rowoff = (int*)take((size_t)(NN + 1) * 4);
    int*   part   = (int*)take(1024 * 4);
    float* Tbuf   = (float*)take((size_t)128 * 64 * 4);
    float* WcT    = (float*)take((size_t)64 * 128 * 4);
    int2*  edgeA  = (int2*)take((size_t)ENT * 8);
    float* h      = (float*)take((size_t)NN * 64 * 4);
    float* y      = (float*)take((size_t)NN * 64 * 4);
    if (off > ws_size) return;   // workspace too small: fail cleanly

    // --- build normalized CSR (by dst) + collapsed weights ---
    hipMemsetAsync(cnt, 0, (size_t)NN * 4, stream);
    probe_kernel<<<1, 64, 0, stream>>>((const unsigned*)edges, flag);
    smallw_kernel<<<1, 256, 0, stream>>>(W1, W2, Tbuf, WcT);
    count_kernel<<<(NE + 255) / 256, 256, 0, stream>>>(edges, flag, cnt);
    dinv_kernel<<<(NN + 255) / 256, 256, 0, stream>>>(cnt, dinv);
    int nb = (NN + 1023) / 1024;   // 98
    scan_local<<<nb, 1024, 0, stream>>>(cnt, rowoff, part);
    scan_part<<<1, 128, 0, stream>>>(part, nb);
    scan_add<<<(NN + 255) / 256, 256, 0, stream>>>(rowoff, cnt, part);
    fill_kernel<<<(ENT + 255) / 256, 256, 0, stream>>>(edges, flag, dinv, cnt, edgeA);

    // --- collapsed network: out = A^3 (X Wc) ---
    const int GB = (NN + 63) / 64;          // 1563
    const int PB = (NN * 64 + 255) / 256;   // 25000 (one wave per node)

    gemm_xwt<64><<<GB, 256, 0, stream>>>(x, WcT, h, NN);
    spmm64_kernel<<<PB, 256, 0, stream>>>(rowoff, edgeA, h, y);
    spmm64_kernel<<<PB, 256, 0, stream>>>(rowoff, edgeA, y, h);
    spmm64_kernel<<<PB, 256, 0, stream>>>(rowoff, edgeA, h, out);
}

// Round 4
// 400.393 us; speedup vs baseline: 1.5395x; 1.5395x over previous
//
#include <hip/hip_runtime.h>

#define NN 100000
#define NE 1600000
#define ENT (NE + NN)   // edges + self loops

// ---------------- CSR build ----------------

__global__ void probe_kernel(const unsigned* __restrict__ edges, int* __restrict__ flag) {
    if (threadIdx.x == 0 && blockIdx.x == 0) {
        int is64 = 1;
        for (int i = 1; i < 64; i += 2)
            if (edges[i] != 0u) { is64 = 0; break; }
        *flag = is64;
    }
}

// count in-degree from the dst half of the raw edge list (int64 or int32)
__global__ void count_kernel(const void* __restrict__ edges, const int* __restrict__ flag,
                             int* __restrict__ cnt) {
    int i = blockIdx.x * blockDim.x + threadIdx.x;
    if (i >= NE) return;
    int d;
    if (*flag) d = (int)((const long long*)edges)[NE + i];
    else       d = ((const int*)edges)[NE + i];
    atomicAdd(&cnt[d], 1);
}

__global__ void dinv_kernel(const int* __restrict__ cnt, float* __restrict__ dinv) {
    int i = blockIdx.x * blockDim.x + threadIdx.x;
    if (i < NN) dinv[i] = rsqrtf((float)(cnt[i] + 1));  // +1 self loop, always > 0
}

__global__ __launch_bounds__(1024) void scan_local(const int* __restrict__ cnt,
                                                   int* __restrict__ rowoff,
                                                   int* __restrict__ part) {
    __shared__ int s[1024];
    int t = threadIdx.x;
    int i = blockIdx.x * 1024 + t;
    int v = (i < NN) ? cnt[i] + 1 : 0;
    s[t] = v;
    __syncthreads();
    for (int off = 1; off < 1024; off <<= 1) {
        int a = (t >= off) ? s[t - off] : 0;
        __syncthreads();
        s[t] += a;
        __syncthreads();
    }
    if (i < NN) rowoff[i] = s[t] - v;     // exclusive (local)
    if (t == 1023) part[blockIdx.x] = s[t];
}

__global__ void scan_part(int* __restrict__ part, int nb) {
    __shared__ int s[128];
    int t = threadIdx.x;
    int v = (t < nb) ? part[t] : 0;
    s[t] = v;
    __syncthreads();
    for (int off = 1; off < 128; off <<= 1) {
        int a = (t >= off) ? s[t - off] : 0;
        __syncthreads();
        s[t] += a;
        __syncthreads();
    }
    if (t < nb) part[t] = s[t] - v;       // exclusive
}

// finalize rowoff AND initialize the fill cursor to the same offsets
__global__ void scan_add(int* __restrict__ rowoff, int* __restrict__ cursor,
                         const int* __restrict__ part) {
    int i = blockIdx.x * blockDim.x + threadIdx.x;
    if (i < NN) {
        int v = rowoff[i] + part[i >> 10];
        rowoff[i] = v;
        cursor[i] = v;
    }
    if (i == 0) rowoff[NN] = ENT;
}

// one packed 8B scatter per edge: (src, norm-bits); reads raw edges directly
__global__ void fill_kernel(const void* __restrict__ edges, const int* __restrict__ flag,
                            const float* __restrict__ dinv,
                            int* __restrict__ cursor, int2* __restrict__ edge) {
    int i = blockIdx.x * blockDim.x + threadIdx.x;
    if (i >= ENT) return;
    int s, j;
    if (i < NE) {
        if (*flag) {
            s = (int)((const long long*)edges)[i];
            j = (int)((const long long*)edges)[NE + i];
        } else {
            s = ((const int*)edges)[i];
            j = ((const int*)edges)[NE + i];
        }
    } else {
        s = i - NE; j = s;
    }
    int p = atomicAdd(&cursor[j], 1);
    float v = dinv[s] * dinv[j];
    edge[p] = make_int2(s, __float_as_int(v));
}

// ---------------- collapsed weights, grid-parallel ----------------
// T[k][j]   = sum_q W1[q][k] * W2[j][q]      (T = W1^T W2^T, [128][64])
// WcT[j][i] = sum_k W1[k][i] * T[k][j]       (Wc = W1^T T, stored transposed [64][128])

__global__ __launch_bounds__(256) void wprod1_kernel(const float* __restrict__ W1,
                                                     const float* __restrict__ W2,
                                                     float* __restrict__ T) {
    int idx = blockIdx.x * blockDim.x + threadIdx.x;
    if (idx >= 128 * 64) return;
    int k = idx >> 6, j = idx & 63;
    float s = 0.f;
    #pragma unroll 8
    for (int q = 0; q < 128; ++q)
        s += W1[q * 128 + k] * W2[j * 128 + q];
    T[k * 64 + j] = s;
}

__global__ __launch_bounds__(256) void wprod2_kernel(const float* __restrict__ W1,
                                                     const float* __restrict__ T,
                                                     float* __restrict__ WcT) {
    int idx = blockIdx.x * blockDim.x + threadIdx.x;
    if (idx >= 128 * 64) return;
    int i = idx >> 6, j = idx & 63;
    float s = 0.f;
    #pragma unroll 8
    for (int k = 0; k < 128; ++k)
        s += W1[k * 128 + i] * T[k * 64 + j];
    WcT[j * 128 + i] = s;
}

// ---------------- propagate (F=64): one wave per node, lane = feature ----------------

__global__ __launch_bounds__(256) void spmm64_kernel(const int* __restrict__ rowoff,
                                                     const int2* __restrict__ edge,
                                                     const float* __restrict__ H,
                                                     float* __restrict__ O) {
    int w = (int)((blockIdx.x * (unsigned)blockDim.x + threadIdx.x) >> 6);
    if (w >= NN) return;
    int lane = threadIdx.x & 63;
    int s = rowoff[w], e = rowoff[w + 1];
    float acc = 0.f;
    const float* base = H + lane;

    int p = s;
    for (; p + 8 <= e; p += 8) {
        int2 E[8];
        #pragma unroll
        for (int q = 0; q < 8; ++q) E[q] = edge[p + q];
        #pragma unroll
        for (int q = 0; q < 8; ++q)
            acc += __int_as_float(E[q].y) * base[(size_t)E[q].x * 64];
    }
    if (p + 4 <= e) {
        int2 E[4];
        #pragma unroll
        for (int q = 0; q < 4; ++q) E[q] = edge[p + q];
        #pragma unroll
        for (int q = 0; q < 4; ++q)
            acc += __int_as_float(E[q].y) * base[(size_t)E[q].x * 64];
        p += 4;
    }
    for (; p < e; ++p) {
        int2 E = edge[p];
        acc += __int_as_float(E.y) * base[(size_t)E.x * 64];
    }
    O[(size_t)w * 64 + lane] = acc;
}

// ---------------- fp32 GEMM: Y[M,N] = X[M,128] @ W[N,128]^T ----------------

template<int N>   // N = 128 or 64
__global__ __launch_bounds__(256) void gemm_xwt(const float* __restrict__ X,
                                                const float* __restrict__ W,
                                                float* __restrict__ Y, int M) {
    constexpr int K = 128, BM = 64, BK = 32;
    constexpr int TM = 4, TN = N / 16;
    __shared__ float Xs[BK][BM + 4];
    __shared__ float Ws[BK][N + 4];
    int t  = threadIdx.x;
    int m0 = blockIdx.x * BM;
    int r0 = (t >> 4) * TM;
    int c0 = (t & 15) * TN;
    float acc[TM][TN] = {};
    for (int k0 = 0; k0 < K; k0 += BK) {
        #pragma unroll
        for (int i = 0; i < 2; ++i) {            // X tile: 512 float4
            int f  = t + i * 256;
            int m  = f >> 3;
            int kq = (f & 7) << 2;
            int gm = m0 + m; if (gm >= M) gm = M - 1;
            float4 v = *(const float4*)&X[(size_t)gm * K + k0 + kq];
            Xs[kq + 0][m] = v.x; Xs[kq + 1][m] = v.y;
            Xs[kq + 2][m] = v.z; Xs[kq + 3][m] = v.w;
        }
        #pragma unroll
        for (int i = 0; i < N / 32; ++i) {       // W tile: N*8 float4
            int f  = t + i * 256;
            int n  = f >> 3;
            int kq = (f & 7) << 2;
            float4 v = *(const float4*)&W[(size_t)n * K + k0 + kq];
            Ws[kq + 0][n] = v.x; Ws[kq + 1][n] = v.y;
            Ws[kq + 2][n] = v.z; Ws[kq + 3][n] = v.w;
        }
        __syncthreads();
        #pragma unroll
        for (int k = 0; k < BK; ++k) {
            float4 xv = *(const float4*)&Xs[k][r0];
            float xf[TM] = {xv.x, xv.y, xv.z, xv.w};
            float wf[TN];
            #pragma unroll
            for (int j = 0; j < TN; j += 4) {
                float4 wv = *(const float4*)&Ws[k][c0 + j];
                wf[j] = wv.x; wf[j + 1] = wv.y; wf[j + 2] = wv.z; wf[j + 3] = wv.w;
            }
            #pragma unroll
            for (int i = 0; i < TM; ++i)
                #pragma unroll
                for (int j = 0; j < TN; ++j)
                    acc[i][j] += xf[i] * wf[j];
        }
        __syncthreads();
    }
    #pragma unroll
    for (int i = 0; i < TM; ++i) {
        int gm = m0 + r0 + i;
        if (gm < M) {
            #pragma unroll
            for (int j = 0; j < TN; j += 4) {
                float4 v = {acc[i][j], acc[i][j + 1], acc[i][j + 2], acc[i][j + 3]};
                *(float4*)&Y[(size_t)gm * N + c0 + j] = v;
            }
        }
    }
}

// ---------------- launch ----------------

extern "C" void kernel_launch(void* const* d_in, const int* in_sizes, int n_in,
                              void* d_out, int out_size, void* d_ws, size_t ws_size,
                              hipStream_t stream) {
    const float* x     = (const float*)d_in[0];
    const void*  edges = d_in[1];
    const float* W1    = (const float*)d_in[2];
    const float* W2    = (const float*)d_in[3];
    float* out = (float*)d_out;

    char* ws = (char*)d_ws;
    size_t off = 0;
    auto take = [&](size_t bytes) -> char* {
        char* p = ws + off;
        off = (off + bytes + 255) & ~(size_t)255;
        return p;
    };
    int*   flag   = (int*)take(4);
    int*   cnt    = (int*)take((size_t)NN * 4);        // degree counts, then fill cursor
    float* dinv   = (float*)take((size_t)NN * 4);
    int*   rowoff = (int*)take((size_t)(NN + 1) * 4);
    int*   part   = (int*)take(1024 * 4);
    float* Tbuf   = (float*)take((size_t)128 * 64 * 4);
    float* WcT    = (float*)take((size_t)64 * 128 * 4);
    int2*  edgeA  = (int2*)take((size_t)ENT * 8);
    float* h      = (float*)take((size_t)NN * 64 * 4);
    float* y      = (float*)take((size_t)NN * 64 * 4);
    if (off > ws_size) return;   // workspace too small: fail cleanly

    // --- build normalized CSR (by dst) + collapsed weights ---
    hipMemsetAsync(cnt, 0, (size_t)NN * 4, stream);
    probe_kernel<<<1, 64, 0, stream>>>((const unsigned*)edges, flag);
    wprod1_kernel<<<32, 256, 0, stream>>>(W1, W2, Tbuf);
    wprod2_kernel<<<32, 256, 0, stream>>>(W1, Tbuf, WcT);
    count_kernel<<<(NE + 255) / 256, 256, 0, stream>>>(edges, flag, cnt);
    dinv_kernel<<<(NN + 255) / 256, 256, 0, stream>>>(cnt, dinv);
    int nb = (NN + 1023) / 1024;   // 98
    scan_local<<<nb, 1024, 0, stream>>>(cnt, rowoff, part);
    scan_part<<<1, 128, 0, stream>>>(part, nb);
    scan_add<<<(NN + 255) / 256, 256, 0, stream>>>(rowoff, cnt, part);
    fill_kernel<<<(ENT + 255) / 256, 256, 0, stream>>>(edges, flag, dinv, cnt, edgeA);

    // --- collapsed network: out = A^3 (X Wc) ---
    const int GB = (NN + 63) / 64;          // 1563
    const int PB = (NN * 64 + 255) / 256;   // 25000 (one wave per node)

    gemm_xwt<64><<<GB, 256, 0, stream>>>(x, WcT, h, NN);
    spmm64_kernel<<<PB, 256, 0, stream>>>(rowoff, edgeA, h, y);
    spmm64_kernel<<<PB, 256, 0, stream>>>(rowoff, edgeA, y, h);
    spmm64_kernel<<<PB, 256, 0, stream>>>(rowoff, edgeA, h, out);
}

// Round 5
// 287.779 us; speedup vs baseline: 2.1419x; 1.3913x over previous
//
#include <hip/hip_runtime.h>

#define NN 100000
#define NE 1600000
#define ENT (NE + NN)      // edges + self loops
#define NB 196             // bins of 512 dst nodes (dst >> 9)
#define BINCAP 10240       // slab capacity per bin (expected ~8192 edges + 512 loops)

// ---------------- int64/int32 edge-dtype probe ----------------

__global__ void probe_kernel(const unsigned* __restrict__ edges, int* __restrict__ flag) {
    if (threadIdx.x == 0 && blockIdx.x == 0) {
        int is64 = 1;
        for (int i = 1; i < 64; i += 2)
            if (edges[i] != 0u) { is64 = 0; break; }
        *flag = is64;
    }
}

// ---------------- pass 1: partition edges into 196 dst-bins ----------------

__global__ __launch_bounds__(256) void part_kernel(const void* __restrict__ edges,
                                                   const int* __restrict__ flag,
                                                   int2* __restrict__ binned,
                                                   int* __restrict__ binCnt) {
    __shared__ int hist[NB], base[NB], rank[NB];
    int t = threadIdx.x;
    for (int i = t; i < NB; i += 256) hist[i] = 0;
    __syncthreads();
    int i0 = blockIdx.x * 4096;
    bool is64 = (*flag != 0);
    int s[16], d[16];
    #pragma unroll
    for (int q = 0; q < 16; ++q) {
        int i = i0 + q * 256 + t;
        if (i < NE) {
            if (is64) {
                s[q] = (int)((const long long*)edges)[i];
                d[q] = (int)((const long long*)edges)[NE + i];
            } else {
                s[q] = ((const int*)edges)[i];
                d[q] = ((const int*)edges)[NE + i];
            }
            atomicAdd(&hist[d[q] >> 9], 1);
        } else d[q] = -1;
    }
    __syncthreads();
    for (int i = t; i < NB; i += 256) {
        base[i] = atomicAdd(&binCnt[i], hist[i]);
        rank[i] = 0;
    }
    __syncthreads();
    #pragma unroll
    for (int q = 0; q < 16; ++q) {
        if (d[q] >= 0) {
            int b = d[q] >> 9;
            int r = base[b] + atomicAdd(&rank[b], 1);
            if (r < BINCAP) binned[(size_t)b * BINCAP + r] = make_int2(s[q], d[q]);
        }
    }
}

// ---------------- pass 2: scan bin totals (edges + self loops) ----------------

__global__ void binscan_kernel(const int* __restrict__ binCnt, int* __restrict__ binOff) {
    __shared__ int sh[256];
    int t = threadIdx.x;
    int nodes = (t < NB) ? ((t == NB - 1) ? (NN - 512 * (NB - 1)) : 512) : 0;
    int v = (t < NB) ? binCnt[t] + nodes : 0;
    sh[t] = v;
    __syncthreads();
    for (int off = 1; off < 256; off <<= 1) {
        int a = (t >= off) ? sh[t - off] : 0;
        __syncthreads();
        sh[t] += a;
        __syncthreads();
    }
    if (t < NB) binOff[t] = sh[t] - v;
    if (t == NB - 1) binOff[NB] = sh[t];   // == ENT
}

// ---------------- pass 3: per-bin degree hist -> dinv + exact rowoff ----------------

__global__ __launch_bounds__(1024) void degscan_kernel(const int2* __restrict__ binned,
                                                       const int* __restrict__ binCnt,
                                                       const int* __restrict__ binOff,
                                                       float* __restrict__ dinv,
                                                       int* __restrict__ rowoff) {
    __shared__ int hist[512];
    __shared__ int sc[512];
    int b = blockIdx.x, t = threadIdx.x;
    int nb0 = b << 9;
    int nNodes = min(512, NN - nb0);
    int cnt = binCnt[b];
    if (t < 512) hist[t] = 0;
    __syncthreads();
    const int2* e = binned + (size_t)b * BINCAP;
    for (int i = t; i < cnt; i += 1024) atomicAdd(&hist[e[i].y - nb0], 1);
    __syncthreads();
    int v = 0;
    if (t < 512) { v = (t < nNodes) ? hist[t] + 1 : 0; sc[t] = v; }
    __syncthreads();
    for (int off = 1; off < 512; off <<= 1) {
        int a = (t >= off && t < 512) ? sc[t - off] : 0;
        __syncthreads();
        if (t < 512) sc[t] += a;
        __syncthreads();
    }
    if (t < nNodes) {
        dinv[nb0 + t] = rsqrtf((float)(hist[t] + 1));
        rowoff[nb0 + t] = binOff[b] + sc[t] - v;
    }
    if (b == NB - 1 && t == 0) rowoff[NN] = ENT;
}

// ---------------- pass 4: per-bin CSR fill via LDS staging, coalesced out ----------------

__global__ __launch_bounds__(1024) void fill2_kernel(const int2* __restrict__ binned,
                                                     const int* __restrict__ binCnt,
                                                     const int* __restrict__ binOff,
                                                     const float* __restrict__ dinv,
                                                     const int* __restrict__ rowoff,
                                                     int2* __restrict__ edge) {
    extern __shared__ char smem[];
    int2* stage = (int2*)smem;                       // BINCAP * 8 B
    int*  cur   = (int*)(smem + (size_t)BINCAP * 8); // 512 * 4 B
    int b = blockIdx.x, t = threadIdx.x;
    int nb0 = b << 9;
    int nNodes = min(512, NN - nb0);
    int cnt = binCnt[b];
    int off0 = binOff[b];
    int total = binOff[b + 1] - off0;
    if (t < nNodes) {
        int lo = rowoff[nb0 + t] - off0;
        float di = dinv[nb0 + t];
        stage[lo] = make_int2(nb0 + t, __float_as_int(di * di));  // self loop first
        cur[t] = lo + 1;
    }
    __syncthreads();
    const int2* e = binned + (size_t)b * BINCAP;
    for (int i = t; i < cnt; i += 1024) {
        int2 sd = e[i];
        int slot = atomicAdd(&cur[sd.y - nb0], 1);
        float v = dinv[sd.x] * dinv[sd.y];
        if (slot < BINCAP) stage[slot] = make_int2(sd.x, __float_as_int(v));
    }
    __syncthreads();
    int2* dst = edge + off0;
    for (int i = t; i < total; i += 1024) dst[i] = stage[i];
}

// ---------------- collapsed weights, grid-parallel ----------------
// T[k][j]   = sum_q W1[q][k] * W2[j][q]      (T = W1^T W2^T, [128][64])
// WcT[j][i] = sum_k W1[k][i] * T[k][j]       (Wc = W1^T T, stored transposed [64][128])

__global__ __launch_bounds__(256) void wprod1_kernel(const float* __restrict__ W1,
                                                     const float* __restrict__ W2,
                                                     float* __restrict__ T) {
    int idx = blockIdx.x * blockDim.x + threadIdx.x;
    if (idx >= 128 * 64) return;
    int k = idx >> 6, j = idx & 63;
    float s = 0.f;
    #pragma unroll 8
    for (int q = 0; q < 128; ++q)
        s += W1[q * 128 + k] * W2[j * 128 + q];
    T[k * 64 + j] = s;
}

__global__ __launch_bounds__(256) void wprod2_kernel(const float* __restrict__ W1,
                                                     const float* __restrict__ T,
                                                     float* __restrict__ WcT) {
    int idx = blockIdx.x * blockDim.x + threadIdx.x;
    if (idx >= 128 * 64) return;
    int i = idx >> 6, j = idx & 63;
    float s = 0.f;
    #pragma unroll 8
    for (int k = 0; k < 128; ++k)
        s += W1[k * 128 + i] * T[k * 64 + j];
    WcT[j * 128 + i] = s;
}

// ---------------- propagate (F=64): one wave per node, lane = feature ----------------

__global__ __launch_bounds__(256) void spmm64_kernel(const int* __restrict__ rowoff,
                                                     const int2* __restrict__ edge,
                                                     const float* __restrict__ H,
                                                     float* __restrict__ O) {
    int w = (int)((blockIdx.x * (unsigned)blockDim.x + threadIdx.x) >> 6);
    if (w >= NN) return;
    int lane = threadIdx.x & 63;
    int s = rowoff[w], e = rowoff[w + 1];
    float acc = 0.f;
    const float* base = H + lane;

    int p = s;
    for (; p + 8 <= e; p += 8) {
        int2 E[8];
        #pragma unroll
        for (int q = 0; q < 8; ++q) E[q] = edge[p + q];
        #pragma unroll
        for (int q = 0; q < 8; ++q)
            acc += __int_as_float(E[q].y) * base[(size_t)E[q].x * 64];
    }
    if (p + 4 <= e) {
        int2 E[4];
        #pragma unroll
        for (int q = 0; q < 4; ++q) E[q] = edge[p + q];
        #pragma unroll
        for (int q = 0; q < 4; ++q)
            acc += __int_as_float(E[q].y) * base[(size_t)E[q].x * 64];
        p += 4;
    }
    for (; p < e; ++p) {
        int2 E = edge[p];
        acc += __int_as_float(E.y) * base[(size_t)E.x * 64];
    }
    O[(size_t)w * 64 + lane] = acc;
}

// ---------------- fp32 GEMM: Y[M,N] = X[M,128] @ W[N,128]^T ----------------

template<int N>   // N = 128 or 64
__global__ __launch_bounds__(256) void gemm_xwt(const float* __restrict__ X,
                                                const float* __restrict__ W,
                                                float* __restrict__ Y, int M) {
    constexpr int K = 128, BM = 64, BK = 32;
    constexpr int TM = 4, TN = N / 16;
    __shared__ float Xs[BK][BM + 4];
    __shared__ float Ws[BK][N + 4];
    int t  = threadIdx.x;
    int m0 = blockIdx.x * BM;
    int r0 = (t >> 4) * TM;
    int c0 = (t & 15) * TN;
    float acc[TM][TN] = {};
    for (int k0 = 0; k0 < K; k0 += BK) {
        #pragma unroll
        for (int i = 0; i < 2; ++i) {            // X tile: 512 float4
            int f  = t + i * 256;
            int m  = f >> 3;
            int kq = (f & 7) << 2;
            int gm = m0 + m; if (gm >= M) gm = M - 1;
            float4 v = *(const float4*)&X[(size_t)gm * K + k0 + kq];
            Xs[kq + 0][m] = v.x; Xs[kq + 1][m] = v.y;
            Xs[kq + 2][m] = v.z; Xs[kq + 3][m] = v.w;
        }
        #pragma unroll
        for (int i = 0; i < N / 32; ++i) {       // W tile: N*8 float4
            int f  = t + i * 256;
            int n  = f >> 3;
            int kq = (f & 7) << 2;
            float4 v = *(const float4*)&W[(size_t)n * K + k0 + kq];
            Ws[kq + 0][n] = v.x; Ws[kq + 1][n] = v.y;
            Ws[kq + 2][n] = v.z; Ws[kq + 3][n] = v.w;
        }
        __syncthreads();
        #pragma unroll
        for (int k = 0; k < BK; ++k) {
            float4 xv = *(const float4*)&Xs[k][r0];
            float xf[TM] = {xv.x, xv.y, xv.z, xv.w};
            float wf[TN];
            #pragma unroll
            for (int j = 0; j < TN; j += 4) {
                float4 wv = *(const float4*)&Ws[k][c0 + j];
                wf[j] = wv.x; wf[j + 1] = wv.y; wf[j + 2] = wv.z; wf[j + 3] = wv.w;
            }
            #pragma unroll
            for (int i = 0; i < TM; ++i)
                #pragma unroll
                for (int j = 0; j < TN; ++j)
                    acc[i][j] += xf[i] * wf[j];
        }
        __syncthreads();
    }
    #pragma unroll
    for (int i = 0; i < TM; ++i) {
        int gm = m0 + r0 + i;
        if (gm < M) {
            #pragma unroll
            for (int j = 0; j < TN; j += 4) {
                float4 v = {acc[i][j], acc[i][j + 1], acc[i][j + 2], acc[i][j + 3]};
                *(float4*)&Y[(size_t)gm * N + c0 + j] = v;
            }
        }
    }
}

// ---------------- launch ----------------

extern "C" void kernel_launch(void* const* d_in, const int* in_sizes, int n_in,
                              void* d_out, int out_size, void* d_ws, size_t ws_size,
                              hipStream_t stream) {
    const float* x     = (const float*)d_in[0];
    const void*  edges = d_in[1];
    const float* W1    = (const float*)d_in[2];
    const float* W2    = (const float*)d_in[3];
    float* out = (float*)d_out;

    char* ws = (char*)d_ws;
    size_t off = 0;
    auto take = [&](size_t bytes) -> char* {
        char* p = ws + off;
        off = (off + bytes + 255) & ~(size_t)255;
        return p;
    };
    int*   flag   = (int*)take(4);
    int*   binCnt = (int*)take((size_t)NB * 4);
    int*   binOff = (int*)take((size_t)(NB + 1) * 4);
    float* dinv   = (float*)take((size_t)NN * 4);
    int*   rowoff = (int*)take((size_t)(NN + 1) * 4);
    float* Tbuf   = (float*)take((size_t)128 * 64 * 4);
    float* WcT    = (float*)take((size_t)64 * 128 * 4);
    int2*  binned = (int2*)take((size_t)NB * BINCAP * 8);
    int2*  edgeA  = (int2*)take((size_t)ENT * 8);
    float* h      = (float*)take((size_t)NN * 64 * 4);
    float* y      = (float*)take((size_t)NN * 64 * 4);
    if (off > ws_size) return;   // workspace too small: fail cleanly

    // --- build normalized CSR (binned two-pass sort) + collapsed weights ---
    hipMemsetAsync(binCnt, 0, (size_t)NB * 4, stream);
    probe_kernel<<<1, 64, 0, stream>>>((const unsigned*)edges, flag);
    wprod1_kernel<<<32, 256, 0, stream>>>(W1, W2, Tbuf);
    wprod2_kernel<<<32, 256, 0, stream>>>(W1, Tbuf, WcT);
    part_kernel<<<(NE + 4095) / 4096, 256, 0, stream>>>(edges, flag, binned, binCnt);
    binscan_kernel<<<1, 256, 0, stream>>>(binCnt, binOff);
    degscan_kernel<<<NB, 1024, 0, stream>>>(binned, binCnt, binOff, dinv, rowoff);
    size_t f2lds = (size_t)BINCAP * 8 + 512 * 4;
    fill2_kernel<<<NB, 1024, f2lds, stream>>>(binned, binCnt, binOff, dinv, rowoff, edgeA);

    // --- collapsed network: out = A^3 (X Wc) ---
    const int GB = (NN + 63) / 64;          // 1563
    const int PB = (NN * 64 + 255) / 256;   // 25000 (one wave per node)

    gemm_xwt<64><<<GB, 256, 0, stream>>>(x, WcT, h, NN);
    spmm64_kernel<<<PB, 256, 0, stream>>>(rowoff, edgeA, h, y);
    spmm64_kernel<<<PB, 256, 0, stream>>>(rowoff, edgeA, y, h);
    spmm64_kernel<<<PB, 256, 0, stream>>>(rowoff, edgeA, h, out);
}

// Round 6
// 262.778 us; speedup vs baseline: 2.3456x; 1.0951x over previous
//
#include <hip/hip_runtime.h>

#define NN 100000
#define NE 1600000
#define ENT (NE + NN)      // edges + self loops
#define NB 196             // bins of 512 dst nodes (dst >> 9)
#define BINCAP 10240       // slab capacity per bin (mean 8192+512, +17 sigma)

// ---------------- probe edge dtype + zero bin counters ----------------

__global__ void probe_zero(const unsigned* __restrict__ edges, int* __restrict__ flag,
                           int* __restrict__ binCnt) {
    int t = threadIdx.x;
    if (t < NB) binCnt[t] = 0;
    if (t == 0) {
        int is64 = 1;
        for (int i = 1; i < 64; i += 2)
            if (edges[i] != 0u) { is64 = 0; break; }
        *flag = is64;
    }
}

// ---------------- pass 1: partition edges into 196 dst-bins (packed ints) ----------------

__global__ __launch_bounds__(256) void part_kernel(const void* __restrict__ edges,
                                                   const int* __restrict__ flag,
                                                   int* __restrict__ binned,
                                                   int* __restrict__ binCnt) {
    __shared__ int hist[NB], base[NB], rank[NB];
    int t = threadIdx.x;
    for (int i = t; i < NB; i += 256) hist[i] = 0;
    __syncthreads();
    int i0 = blockIdx.x * 4096;
    bool is64 = (*flag != 0);
    int s[16], d[16];
    #pragma unroll
    for (int q = 0; q < 16; ++q) {
        int i = i0 + q * 256 + t;
        if (i < NE) {
            if (is64) {
                s[q] = (int)__builtin_nontemporal_load(&((const long long*)edges)[i]);
                d[q] = (int)__builtin_nontemporal_load(&((const long long*)edges)[NE + i]);
            } else {
                s[q] = __builtin_nontemporal_load(&((const int*)edges)[i]);
                d[q] = __builtin_nontemporal_load(&((const int*)edges)[NE + i]);
            }
            atomicAdd(&hist[d[q] >> 9], 1);
        } else d[q] = -1;
    }
    __syncthreads();
    for (int i = t; i < NB; i += 256) {
        base[i] = atomicAdd(&binCnt[i], hist[i]);
        rank[i] = 0;
    }
    __syncthreads();
    #pragma unroll
    for (int q = 0; q < 16; ++q) {
        if (d[q] >= 0) {
            int b = d[q] >> 9;
            int r = base[b] + atomicAdd(&rank[b], 1);
            if (r < BINCAP)
                binned[(size_t)b * BINCAP + r] = ((d[q] & 511) << 17) | s[q];
        }
    }
}

// ---------------- pass 2: per-bin degree hist -> dinv, rowoff, sorted CSR ----------------

__global__ __launch_bounds__(1024) void build2_kernel(const int* __restrict__ binCnt,
                                                      const int* __restrict__ binned,
                                                      float* __restrict__ dinv,
                                                      int* __restrict__ rowoff,
                                                      int* __restrict__ edge) {
    extern __shared__ char smem[];
    int* stage = (int*)smem;                       // BINCAP
    int* hist  = (int*)(smem + (size_t)BINCAP * 4); // 512
    int* sc    = hist + 512;                        // 512
    int* cur   = sc + 512;                          // 512
    int* bsc   = cur + 512;                         // 256
    int b = blockIdx.x, t = threadIdx.x;
    int nb0 = b << 9;
    int nNodes = min(512, NN - nb0);

    // local exclusive scan of (binCnt + nodes) to recover this bin's global offset
    if (t < 256) {
        int nodes = (t < NB) ? min(512, NN - (t << 9)) : 0;
        bsc[t] = (t < NB) ? binCnt[t] + nodes : 0;
    }
    if (t < 512) hist[t] = 0;
    __syncthreads();
    for (int off = 1; off < 256; off <<= 1) {
        int a = (t < 256 && t >= off) ? bsc[t - off] : 0;
        __syncthreads();
        if (t < 256) bsc[t] += a;
        __syncthreads();
    }
    int cntRaw = binCnt[b];
    int cnt = min(cntRaw, BINCAP);
    int off0 = bsc[b] - (cntRaw + nNodes);   // exclusive prefix

    const int* e = binned + (size_t)b * BINCAP;
    for (int i = t; i < cnt; i += 1024) atomicAdd(&hist[e[i] >> 17], 1);
    __syncthreads();
    int v = 0;
    if (t < 512) { v = (t < nNodes) ? hist[t] + 1 : 0; sc[t] = v; }
    __syncthreads();
    for (int off = 1; off < 512; off <<= 1) {
        int a = (t < 512 && t >= off) ? sc[t - off] : 0;
        __syncthreads();
        if (t < 512) sc[t] += a;
        __syncthreads();
    }
    if (t < nNodes) {
        dinv[nb0 + t] = rsqrtf((float)(hist[t] + 1));
        int lo = sc[t] - v;
        rowoff[nb0 + t] = off0 + lo;
        stage[lo] = nb0 + t;        // self loop first
        cur[t] = lo + 1;
    }
    if (b == NB - 1 && t == 0) rowoff[NN] = ENT;
    __syncthreads();
    for (int i = t; i < cnt; i += 1024) {
        int pk = e[i];
        int slot = atomicAdd(&cur[pk >> 17], 1);
        if (slot < BINCAP) stage[slot] = pk & 0x1FFFF;
    }
    __syncthreads();
    int total = min(cntRaw + nNodes, BINCAP);
    int* dst = edge + off0;
    for (int i = t; i < total; i += 1024) dst[i] = stage[i];
}

// ---------------- collapsed weights, grid-parallel ----------------
// T[k][j]   = sum_q W1[q][k] * W2[j][q]      (T = W1^T W2^T, [128][64])
// WcT[j][i] = sum_k W1[k][i] * T[k][j]       (Wc = W1^T T, stored transposed [64][128])

__global__ __launch_bounds__(256) void wprod1_kernel(const float* __restrict__ W1,
                                                     const float* __restrict__ W2,
                                                     float* __restrict__ T) {
    int idx = blockIdx.x * blockDim.x + threadIdx.x;
    if (idx >= 128 * 64) return;
    int k = idx >> 6, j = idx & 63;
    float s = 0.f;
    #pragma unroll 8
    for (int q = 0; q < 128; ++q)
        s += W1[q * 128 + k] * W2[j * 128 + q];
    T[k * 64 + j] = s;
}

__global__ __launch_bounds__(256) void wprod2_kernel(const float* __restrict__ W1,
                                                     const float* __restrict__ T,
                                                     float* __restrict__ WcT) {
    int idx = blockIdx.x * blockDim.x + threadIdx.x;
    if (idx >= 128 * 64) return;
    int i = idx >> 6, j = idx & 63;
    float s = 0.f;
    #pragma unroll 8
    for (int k = 0; k < 128; ++k)
        s += W1[k * 128 + i] * T[k * 64 + j];
    WcT[j * 128 + i] = s;
}

// ---------------- propagate (F=64): unweighted gather-sum + dinv^SPOW epilogue ----------------

template<int SPOW>
__global__ __launch_bounds__(256) void spmm64f_kernel(const int* __restrict__ rowoff,
                                                      const int* __restrict__ col,
                                                      const float* __restrict__ dinv,
                                                      const float* __restrict__ H,
                                                      float* __restrict__ O) {
    int w = (int)((blockIdx.x * (unsigned)blockDim.x + threadIdx.x) >> 6);
    if (w >= NN) return;
    int lane = threadIdx.x & 63;
    int s = __builtin_amdgcn_readfirstlane(rowoff[w]);
    int e = __builtin_amdgcn_readfirstlane(rowoff[w + 1]);
    float acc = 0.f;
    const float* base = H + lane;

    int p = s;
    for (; p + 8 <= e; p += 8) {
        int c[8];
        #pragma unroll
        for (int q = 0; q < 8; ++q) c[q] = __builtin_nontemporal_load(&col[p + q]);
        #pragma unroll
        for (int q = 0; q < 8; ++q) acc += base[(size_t)c[q] * 64];
    }
    if (p + 4 <= e) {
        int c[4];
        #pragma unroll
        for (int q = 0; q < 4; ++q) c[q] = __builtin_nontemporal_load(&col[p + q]);
        #pragma unroll
        for (int q = 0; q < 4; ++q) acc += base[(size_t)c[q] * 64];
        p += 4;
    }
    for (; p < e; ++p) acc += base[(size_t)__builtin_nontemporal_load(&col[p]) * 64];

    float di = dinv[w];
    float scale = (SPOW == 2) ? di * di : di;
    __builtin_nontemporal_store(acc * scale, &O[(size_t)w * 64 + lane]);
}

// ---------------- fp32 GEMM: G[M,64] = dinv[m] * (X[M,128] @ W[64,128]^T) ----------------

__global__ __launch_bounds__(256) void gemm_xwt64_kernel(const float* __restrict__ X,
                                                         const float* __restrict__ W,
                                                         const float* __restrict__ dinv,
                                                         float* __restrict__ Y, int M) {
    constexpr int N = 64, K = 128, BM = 64, BK = 32;
    constexpr int TM = 4, TN = N / 16;
    __shared__ float Xs[BK][BM + 4];
    __shared__ float Ws[BK][N + 4];
    int t  = threadIdx.x;
    int m0 = blockIdx.x * BM;
    int r0 = (t >> 4) * TM;
    int c0 = (t & 15) * TN;
    float acc[TM][TN] = {};
    for (int k0 = 0; k0 < K; k0 += BK) {
        #pragma unroll
        for (int i = 0; i < 2; ++i) {            // X tile: 512 float4
            int f  = t + i * 256;
            int m  = f >> 3;
            int kq = (f & 7) << 2;
            int gm = m0 + m; if (gm >= M) gm = M - 1;
            float4 v = *(const float4*)&X[(size_t)gm * K + k0 + kq];
            Xs[kq + 0][m] = v.x; Xs[kq + 1][m] = v.y;
            Xs[kq + 2][m] = v.z; Xs[kq + 3][m] = v.w;
        }
        #pragma unroll
        for (int i = 0; i < N / 32; ++i) {       // W tile
            int f  = t + i * 256;
            int n  = f >> 3;
            int kq = (f & 7) << 2;
            float4 v = *(const float4*)&W[(size_t)n * K + k0 + kq];
            Ws[kq + 0][n] = v.x; Ws[kq + 1][n] = v.y;
            Ws[kq + 2][n] = v.z; Ws[kq + 3][n] = v.w;
        }
        __syncthreads();
        #pragma unroll
        for (int k = 0; k < BK; ++k) {
            float4 xv = *(const float4*)&Xs[k][r0];
            float xf[TM] = {xv.x, xv.y, xv.z, xv.w};
            float wf[TN];
            #pragma unroll
            for (int j = 0; j < TN; j += 4) {
                float4 wv = *(const float4*)&Ws[k][c0 + j];
                wf[j] = wv.x; wf[j + 1] = wv.y; wf[j + 2] = wv.z; wf[j + 3] = wv.w;
            }
            #pragma unroll
            for (int i = 0; i < TM; ++i)
                #pragma unroll
                for (int j = 0; j < TN; ++j)
                    acc[i][j] += xf[i] * wf[j];
        }
        __syncthreads();
    }
    #pragma unroll
    for (int i = 0; i < TM; ++i) {
        int gm = m0 + r0 + i;
        if (gm < M) {
            float di = dinv[gm];
            #pragma unroll
            for (int j = 0; j < TN; j += 4) {
                float4 v = {di * acc[i][j], di * acc[i][j + 1],
                            di * acc[i][j + 2], di * acc[i][j + 3]};
                *(float4*)&Y[(size_t)gm * N + c0 + j] = v;
            }
        }
    }
}

// ---------------- launch ----------------

extern "C" void kernel_launch(void* const* d_in, const int* in_sizes, int n_in,
                              void* d_out, int out_size, void* d_ws, size_t ws_size,
                              hipStream_t stream) {
    const float* x     = (const float*)d_in[0];
    const void*  edges = d_in[1];
    const float* W1    = (const float*)d_in[2];
    const float* W2    = (const float*)d_in[3];
    float* out = (float*)d_out;

    char* ws = (char*)d_ws;
    size_t off = 0;
    auto take = [&](size_t bytes) -> char* {
        char* p = ws + off;
        off = (off + bytes + 255) & ~(size_t)255;
        return p;
    };
    int*   flag   = (int*)take(4);
    int*   binCnt = (int*)take((size_t)NB * 4);
    float* dinv   = (float*)take((size_t)NN * 4);
    int*   rowoff = (int*)take((size_t)(NN + 1) * 4);
    float* Tbuf   = (float*)take((size_t)128 * 64 * 4);
    float* WcT    = (float*)take((size_t)64 * 128 * 4);
    int*   binned = (int*)take((size_t)NB * BINCAP * 4);
    int*   edgeA  = (int*)take((size_t)ENT * 4);
    float* g      = (float*)take((size_t)NN * 64 * 4);
    float* y      = (float*)take((size_t)NN * 64 * 4);
    if (off > ws_size) return;   // workspace too small: fail cleanly

    // --- build: probe+zero, weights, partition, per-bin CSR ---
    probe_zero<<<1, 256, 0, stream>>>((const unsigned*)edges, flag, binCnt);
    wprod1_kernel<<<32, 256, 0, stream>>>(W1, W2, Tbuf);
    wprod2_kernel<<<32, 256, 0, stream>>>(W1, Tbuf, WcT);
    part_kernel<<<(NE + 4095) / 4096, 256, 0, stream>>>(edges, flag, binned, binCnt);
    size_t b2lds = (size_t)BINCAP * 4 + (512 * 3 + 256) * 4;
    build2_kernel<<<NB, 1024, b2lds, stream>>>(binCnt, binned, dinv, rowoff, edgeA);

    // --- collapsed network: out = D^-1/2 Ab D^-1 Ab D^-1 Ab D^-1/2 (X Wc) ---
    const int GB = (NN + 63) / 64;          // 1563
    const int PB = (NN * 64 + 255) / 256;   // 25000 (one wave per node)

    gemm_xwt64_kernel<<<GB, 256, 0, stream>>>(x, WcT, dinv, g, NN);
    spmm64f_kernel<2><<<PB, 256, 0, stream>>>(rowoff, edgeA, dinv, g, y);
    spmm64f_kernel<2><<<PB, 256, 0, stream>>>(rowoff, edgeA, dinv, y, g);
    spmm64f_kernel<1><<<PB, 256, 0, stream>>>(rowoff, edgeA, dinv, g, out);
}